// Round 13
// baseline (847.235 us; speedup 1.0000x reference)
//
#include <hip/hip_runtime.h>
#include <stdint.h>

#define BATCH 8
#define NPTS 8192
#define NGRP 512
#define KNN 32
#define NCH 6

#define FPS_T 256
#define FPS_PPT (NPTS / FPS_T)   // 32 points per thread
#define PAIRS (FPS_PPT / 2)      // 16 packed pairs
#define FPS_NW (FPS_T / 64)      // 4 waves

#define NBLK 248                 // <= 256, 1 block/CU (LDS) => all co-resident
#define KNN_WAVES ((NBLK - BATCH) * FPS_NW)   // 960

typedef float f2 __attribute__((ext_vector_type(2)));

// packed f32 ops (VOP3P): 2 points per instruction, IEEE rn per lane —
// bit-identical to scalar __fadd_rn/__fmul_rn. add(x,-c) == sub(x,c) exactly.
__device__ __forceinline__ f2 pk_add(f2 a, f2 b) {
    f2 d;
    asm("v_pk_add_f32 %0, %1, %2" : "=v"(d) : "v"(a), "v"(b));
    return d;
}
__device__ __forceinline__ f2 pk_mul(f2 a, f2 b) {
    f2 d;
    asm("v_pk_mul_f32 %0, %1, %2" : "=v"(d) : "v"(a), "v"(b));
    return d;
}

__device__ __forceinline__ unsigned long long max64(unsigned long long a,
                                                    unsigned long long b) {
    return (a > b) ? a : b;
}

// 64-bit max butterfly stage via DPP (xor pattern within a quad):
// 0xB1 = quad_perm [1,0,3,2] (xor 1), 0x4E = quad_perm [2,3,0,1] (xor 2).
template <int CTRL>
__device__ __forceinline__ unsigned long long dpp_max64(unsigned long long k) {
    int lo = (int)(unsigned)k;
    int hi = (int)(unsigned)(k >> 32);
    int plo = __builtin_amdgcn_update_dpp(lo, lo, CTRL, 0xF, 0xF, false);
    int phi = __builtin_amdgcn_update_dpp(hi, hi, CTRL, 0xF, 0xF, false);
    unsigned long long o =
        ((unsigned long long)(unsigned)phi << 32) | (unsigned)plo;
    return max64(o, k);
}

// --------- kNN key: exact reference einsum numerics ---------
// xx: separate numpy ufuncs (x**2 then sum) -> sequential rounded ops.
// dot: einsum inner loop FMA-contracted ascending: fma(cz,z, fma(cy,y, rn(cx*x)))
__device__ __forceinline__ unsigned long long knn_key(const float* __restrict__ base,
                                                      int p, float cx, float cy,
                                                      float cz, float cc) {
    float x = base[p * NCH + 0];
    float y = base[p * NCH + 1];
    float z = base[p * NCH + 2];
    float xx = __fadd_rn(__fadd_rn(__fmul_rn(x, x), __fmul_rn(y, y)), __fmul_rn(z, z));
    float dt = fmaf(cz, z, fmaf(cy, y, __fmul_rn(cx, x)));
    float d2 = __fsub_rn(__fadd_rn(cc, xx), __fmul_rn(2.0f, dt));
    unsigned int bits = __float_as_uint(d2);
    unsigned int ord = bits ^ ((unsigned)((int)bits >> 31) | 0x80000000u);
    return ((unsigned long long)ord << 13) | (unsigned)p;
}

// --------- fused producer-consumer kernel ---------
// blocks [0,8): FPS, one per batch. blocks [8,248): kNN consumers (s_sleep
// spin — hot spinning at scale trips the power governor, R7/R8 evidence).
// FPS reduce redesigned to minimize dependent-chain length (R12 lesson:
// serial-path instructions cost ~3-10 cyc each at 1 wave/SIMD):
//   4-striped (v,j) accumulators (8-deep chains) -> 4 key packs -> 3 max64
//   -> 2 quad-DPP stages -> 1 LDS atomicMax per quad -> barrier -> 1 read.
__global__ __launch_bounds__(FPS_T) void fused_kernel(const float* __restrict__ pts,
                                                      float* __restrict__ out_ctr,
                                                      float* __restrict__ out_nb,
                                                      unsigned int* __restrict__ faridx,
                                                      int fstride) {
    __shared__ float xs[NPTS], ys[NPTS], zs[NPTS];
    __shared__ float ctr_lds[NGRP * 3];
    __shared__ unsigned long long bslot[2];

    const int tid = threadIdx.x;

    if (blockIdx.x < BATCH) {
        // ================= FPS role =================
        const int b = blockIdx.x;
        const float* base = pts + (size_t)b * NPTS * NCH;

        f2 x2[PAIRS], y2[PAIRS], z2[PAIRS], dist2[PAIRS];
#pragma unroll
        for (int i = 0; i < PAIRS; ++i) {
            int p0 = tid + (2 * i) * FPS_T;
            int p1 = tid + (2 * i + 1) * FPS_T;
            float xa = base[p0 * NCH + 0], ya = base[p0 * NCH + 1], za = base[p0 * NCH + 2];
            float xb = base[p1 * NCH + 0], yb = base[p1 * NCH + 1], zb = base[p1 * NCH + 2];
            x2[i] = (f2){xa, xb};
            y2[i] = (f2){ya, yb};
            z2[i] = (f2){za, zb};
            dist2[i] = (f2){1e10f, 1e10f};
            xs[p0] = xa; ys[p0] = ya; zs[p0] = za;
            xs[p1] = xb; ys[p1] = yb; zs[p1] = zb;
        }
        if (tid == 0) { bslot[0] = 0ULL; bslot[1] = 0ULL; }
        __syncthreads();

        int far = 0;
        const int lane = tid & 63;

        for (int g = 0; g < NGRP; ++g) {
            // centroid for group g = point `far` (known at top of iter g)
            float cx = xs[far], cy = ys[far], cz = zs[far];
            if (tid == 0) {
                ctr_lds[g * 3 + 0] = cx;
                ctr_lds[g * 3 + 1] = cy;
                ctr_lds[g * 3 + 2] = cz;
                // publish index -> unblocks this center's kNN wave. relaxed is
                // enough: the index alone determines the centroid (pts is
                // read-only device-wide).
                __hip_atomic_store(&faridx[(b * NGRP + g) * fstride], (unsigned)far,
                                   __ATOMIC_RELAXED, __HIP_MEMORY_SCOPE_AGENT);
                bslot[(g + 1) & 1] = 0ULL;   // reset next iter's slot (off-path)
            }
            if (g == NGRP - 1) break;   // no further update needed

            f2 ncx = (f2){-cx, -cx};
            f2 ncy = (f2){-cy, -cy};
            f2 ncz = (f2){-cz, -cz};

            // ---- update + 4-striped argmax accumulators ----
            // numpy semantics: (dx^2 + dy^2) + dz^2, each op rn, no FMA.
            // stripes: a0 = nd0 of even i, a1 = nd1 of even i,
            //          a2 = nd0 of odd i,  a3 = nd1 of odd i.
            // strict > ascending i keeps smallest j within each stripe;
            // cross-stripe/lane/wave ties resolved by key (8191-p) below.
            float v0 = -1.0f, v1 = -1.0f, v2v = -1.0f, v3 = -1.0f;
            int j0 = 0, j1 = 0, j2 = 0, j3 = 0;
#pragma unroll
            for (int i = 0; i < PAIRS; ++i) {
                f2 dx = pk_add(x2[i], ncx);
                f2 dy = pk_add(y2[i], ncy);
                f2 dz = pk_add(z2[i], ncz);
                f2 sx = pk_mul(dx, dx);
                f2 sy = pk_mul(dy, dy);
                f2 t  = pk_add(sx, sy);
                f2 sz = pk_mul(dz, dz);
                f2 d  = pk_add(t, sz);
                float nd0 = fminf(dist2[i].x, d.x);
                float nd1 = fminf(dist2[i].y, d.y);
                dist2[i].x = nd0;
                dist2[i].y = nd1;
                if (i & 1) {
                    if (nd0 > v2v) { v2v = nd0; j2 = 2 * i; }
                    if (nd1 > v3)  { v3  = nd1; j3 = 2 * i + 1; }
                } else {
                    if (nd0 > v0)  { v0  = nd0; j0 = 2 * i; }
                    if (nd1 > v1)  { v1  = nd1; j1 = 2 * i + 1; }
                }
            }

            // ---- pack 4 keys, merge (2 levels), quad-DPP, LDS atomicMax ----
            // key = (dist bits << 13) | (8191 - p); dist >= 0 -> monotone;
            // larger low word = smaller p = numpy first-occurrence argmax.
            unsigned long long k0 =
                ((unsigned long long)__float_as_uint(v0) << 13) |
                (unsigned)(8191 - (tid + j0 * FPS_T));
            unsigned long long k1 =
                ((unsigned long long)__float_as_uint(v1) << 13) |
                (unsigned)(8191 - (tid + j1 * FPS_T));
            unsigned long long k2 =
                ((unsigned long long)__float_as_uint(v2v) << 13) |
                (unsigned)(8191 - (tid + j2 * FPS_T));
            unsigned long long k3 =
                ((unsigned long long)__float_as_uint(v3) << 13) |
                (unsigned)(8191 - (tid + j3 * FPS_T));
            unsigned long long k = max64(max64(k0, k1), max64(k2, k3));

            k = dpp_max64<0xB1>(k);   // xor 1 within quad
            k = dpp_max64<0x4E>(k);   // xor 2 within quad -> quad max, all 4 lanes
            if ((lane & 3) == 0) atomicMax(&bslot[g & 1], k);
            __syncthreads();

            far = 8191 - (int)(bslot[g & 1] & 0x1FFFULL);
        }

        __syncthreads();   // ctr_lds[last] written by tid 0
        // flush centroids to global, coalesced
        float* ctr = out_ctr + (size_t)b * NGRP * 3;
        for (int i = tid; i < NGRP * 3; i += FPS_T) ctr[i] = ctr_lds[i];

    } else {
        // ================= kNN role (R6-proven, s_sleep spin) =================
        const int wid  = tid >> 6;
        const int lane = tid & 63;
        const int W = (blockIdx.x - BATCH) * FPS_NW + wid;   // [0, 960)

        // enumerate centers in ascending-g order (availability order):
        // e = g*8 + b  ->  wave W handles e = W, W+960, ...
        for (int e = W; e < BATCH * NGRP; e += KNN_WAVES) {
            const int g  = e >> 3;
            const int b  = e & 7;
            const int bg = b * NGRP + g;
            const float* base = pts + (size_t)b * NPTS * NCH;

            // spin until fps publishes this center's index
            unsigned fidx;
            if (lane == 0) {
                while ((fidx = __hip_atomic_load(&faridx[bg * fstride],
                                                 __ATOMIC_RELAXED,
                                                 __HIP_MEMORY_SCOPE_AGENT)) == 0xFFFFFFFFu)
                    __builtin_amdgcn_s_sleep(8);
            }
            fidx = (unsigned)__shfl((int)fidx, 0, 64);

            const float cx = base[fidx * NCH + 0];
            const float cy = base[fidx * NCH + 1];
            const float cz = base[fidx * NCH + 2];
            const float cc = __fadd_rn(__fadd_rn(__fmul_rn(cx, cx), __fmul_rn(cy, cy)),
                                       __fmul_rn(cz, cz));

            // chunk 0 -> bitonic sort 64 keys across the wave
            unsigned long long R = knn_key(base, lane, cx, cy, cz, cc);
#pragma unroll
            for (int k = 2; k <= 64; k <<= 1) {
#pragma unroll
                for (int j = k >> 1; j > 0; j >>= 1) {
                    unsigned long long o = __shfl_xor(R, j, 64);
                    bool takeMin = (((lane & k) == 0) == ((lane & j) == 0));
                    unsigned long long mn = (o < R) ? o : R;
                    unsigned long long mx = (o < R) ? R : o;
                    R = takeMin ? mn : mx;
                }
            }
            unsigned long long R31 = __shfl(R, 31, 64);

            // stream remaining chunks; insert candidates beating current 32nd
            for (int c = 1; c < NPTS / 64; ++c) {
                unsigned long long key = knn_key(base, c * 64 + lane, cx, cy, cz, cc);
                unsigned long long qual = __ballot(key < R31);
                while (qual) {
                    int src = __ffsll(qual) - 1;
                    qual &= qual - 1;
                    unsigned long long bk = __shfl(key, src, 64);
                    int rank = __popcll(__ballot(R < bk));
                    unsigned long long Rp = __shfl_up(R, 1, 64);
                    R = (lane == rank) ? bk : ((lane > rank) ? Rp : R);
                    R31 = __shfl(R, 31, 64);
                }
            }

            // gather: lanes 0..31 hold the sorted top-32
            if (lane < KNN) {
                int idx = (int)(R & 8191ULL);
                const float* s = base + (size_t)idx * NCH;
                float* d = out_nb + ((size_t)bg * KNN + lane) * NCH;
                d[0] = s[0] - cx;
                d[1] = s[1] - cy;
                d[2] = s[2] - cz;
                d[3] = s[3];
                d[4] = s[4];
                d[5] = s[5];
            }
        }
    }
}

extern "C" void kernel_launch(void* const* d_in, const int* in_sizes, int n_in,
                              void* d_out, int out_size, void* d_ws, size_t ws_size,
                              hipStream_t stream) {
    const float* pts = (const float*)d_in[0];
    float* out = (float*)d_out;
    float* out_nb  = out;                                    // (8,512,32,6)
    float* out_ctr = out + (size_t)BATCH * NGRP * KNN * NCH; // (8,512,3)

    // per-center published index; 64B stride => 1 writer + 1 reader per line
    const size_t nctr = (size_t)BATCH * NGRP;
    int fstride = (ws_size >= nctr * 16 * sizeof(unsigned)) ? 16 : 1;
    unsigned int* faridx = (unsigned int*)d_ws;

    hipMemsetAsync(d_ws, 0xFF, nctr * (size_t)fstride * sizeof(unsigned), stream);
    hipLaunchKernelGGL(fused_kernel, dim3(NBLK), dim3(FPS_T), 0, stream,
                       pts, out_ctr, out_nb, faridx, fstride);
}

// Round 15
// 518.391 us; speedup vs baseline: 1.6344x; 1.6344x over previous
//
#include <hip/hip_runtime.h>
#include <stdint.h>

#define BATCH 8
#define NPTS 8192
#define NGRP 512
#define KNN 32
#define NCH 6

#define FPS_T 256
#define FPS_PPT (NPTS / FPS_T)   // 32 points per thread
#define PAIRS (FPS_PPT / 2)      // 16 packed pairs
#define FPS_NW (FPS_T / 64)      // 4 waves

#define NBLK 248                 // <= 256, 1 block/CU (LDS) => all co-resident
#define KNN_WAVES ((NBLK - BATCH) * FPS_NW)   // 960

typedef float f2 __attribute__((ext_vector_type(2)));

// packed f32 ops (VOP3P): 2 points per instruction, IEEE rn per lane —
// bit-identical to scalar __fadd_rn/__fmul_rn. add(x,-c)==sub(x,c) exactly.
// NOTE: no v_pk_min_f32 on gfx950 (R14 compile error) — min stays scalar.
__device__ __forceinline__ f2 pk_add(f2 a, f2 b) {
    f2 d;
    asm("v_pk_add_f32 %0, %1, %2" : "=v"(d) : "v"(a), "v"(b));
    return d;
}
__device__ __forceinline__ f2 pk_mul(f2 a, f2 b) {
    f2 d;
    asm("v_pk_mul_f32 %0, %1, %2" : "=v"(d) : "v"(a), "v"(b));
    return d;
}

__device__ __forceinline__ unsigned long long max64(unsigned long long a,
                                                    unsigned long long b) {
    return (a > b) ? a : b;
}

// 64-bit max butterfly stage via DPP only (no LDS-pipe shuffles).
// Directional reduce: row_shr 1/2/4/8 then row_bcast 15/31 -> lane 63 of the
// wave holds the max. Invalid lanes keep old (= own value) -> max is a no-op.
template <int CTRL>
__device__ __forceinline__ unsigned long long dpp_max64(unsigned long long k) {
    int lo = (int)(unsigned)k;
    int hi = (int)(unsigned)(k >> 32);
    int plo = __builtin_amdgcn_update_dpp(lo, lo, CTRL, 0xF, 0xF, false);
    int phi = __builtin_amdgcn_update_dpp(hi, hi, CTRL, 0xF, 0xF, false);
    unsigned long long o =
        ((unsigned long long)(unsigned)phi << 32) | (unsigned)plo;
    return max64(o, k);
}

__device__ __forceinline__ unsigned long long wave_max_dir(unsigned long long k) {
    k = dpp_max64<0x111>(k);   // row_shr:1
    k = dpp_max64<0x112>(k);   // row_shr:2
    k = dpp_max64<0x114>(k);   // row_shr:4
    k = dpp_max64<0x118>(k);   // row_shr:8
    k = dpp_max64<0x142>(k);   // row_bcast:15
    k = dpp_max64<0x143>(k);   // row_bcast:31
    return k;
}

// --------- kNN key: exact reference einsum numerics ---------
// xx: separate numpy ufuncs (x**2 then sum) -> sequential rounded ops.
// dot: einsum inner loop FMA-contracted ascending: fma(cz,z, fma(cy,y, rn(cx*x)))
__device__ __forceinline__ unsigned long long knn_key(const float* __restrict__ base,
                                                      int p, float cx, float cy,
                                                      float cz, float cc) {
    float x = base[p * NCH + 0];
    float y = base[p * NCH + 1];
    float z = base[p * NCH + 2];
    float xx = __fadd_rn(__fadd_rn(__fmul_rn(x, x), __fmul_rn(y, y)), __fmul_rn(z, z));
    float dt = fmaf(cz, z, fmaf(cy, y, __fmul_rn(cx, x)));
    float d2 = __fsub_rn(__fadd_rn(cc, xx), __fmul_rn(2.0f, dt));
    unsigned int bits = __float_as_uint(d2);
    unsigned int ord = bits ^ ((unsigned)((int)bits >> 31) | 0x80000000u);
    return ((unsigned long long)ord << 13) | (unsigned)p;
}

// --------- fused producer-consumer kernel ---------
// blocks [0,8): FPS, one per batch. blocks [8,248): kNN consumers (s_sleep
// spin). R6 anchor structure: sequential if-chain argmax (hides in the pair
// chains' latency shadows — R12/R13 showed "faster" selection structures
// only add visible issue work), DPP wave reduce, per-wave slots, 1 barrier.
__global__ __launch_bounds__(FPS_T) void fused_kernel(const float* __restrict__ pts,
                                                      float* __restrict__ out_ctr,
                                                      float* __restrict__ out_nb,
                                                      unsigned int* __restrict__ faridx,
                                                      int fstride) {
    __shared__ float p3[NPTS * 3];          // interleaved xyz, 12B stride
    __shared__ float ctr_lds[NGRP * 3];
    __shared__ unsigned long long slots[2][FPS_NW];

    const int tid = threadIdx.x;

    if (blockIdx.x < BATCH) {
        // ================= FPS role =================
        const int b = blockIdx.x;
        const float* base = pts + (size_t)b * NPTS * NCH;

        f2 x2[PAIRS], y2[PAIRS], z2[PAIRS], dist2[PAIRS];
#pragma unroll
        for (int i = 0; i < PAIRS; ++i) {
            int p0 = tid + (2 * i) * FPS_T;
            int p1 = tid + (2 * i + 1) * FPS_T;
            float xa = base[p0 * NCH + 0], ya = base[p0 * NCH + 1], za = base[p0 * NCH + 2];
            float xb = base[p1 * NCH + 0], yb = base[p1 * NCH + 1], zb = base[p1 * NCH + 2];
            x2[i] = (f2){xa, xb};
            y2[i] = (f2){ya, yb};
            z2[i] = (f2){za, zb};
            dist2[i] = (f2){1e10f, 1e10f};
            p3[p0 * 3 + 0] = xa; p3[p0 * 3 + 1] = ya; p3[p0 * 3 + 2] = za;
            p3[p1 * 3 + 0] = xb; p3[p1 * 3 + 1] = yb; p3[p1 * 3 + 2] = zb;
        }
        __syncthreads();

        int far = 0;
        const int wid  = tid >> 6;
        const int lane = tid & 63;

        for (int g = 0; g < NGRP; ++g) {
            // centroid for group g = point `far`: packed LDS broadcast
            // (3 consecutive words in one 12B line, same addr all lanes)
            float cx = p3[far * 3 + 0];
            float cy = p3[far * 3 + 1];
            float cz = p3[far * 3 + 2];
            if (tid == 0) {
                ctr_lds[g * 3 + 0] = cx;
                ctr_lds[g * 3 + 1] = cy;
                ctr_lds[g * 3 + 2] = cz;
                // publish index -> unblocks this center's kNN wave. relaxed is
                // enough: the index alone determines the centroid (pts is
                // read-only device-wide). The store completes during the
                // update loop, so the pre-barrier vmcnt drain is free.
                __hip_atomic_store(&faridx[(b * NGRP + g) * fstride], (unsigned)far,
                                   __ATOMIC_RELAXED, __HIP_MEMORY_SCOPE_AGENT);
            }
            if (g == NGRP - 1) break;   // no further update needed

            f2 ncx = (f2){-cx, -cx};
            f2 ncy = (f2){-cy, -cy};
            f2 ncz = (f2){-cz, -cz};

            // min-dist update + argmax (ascending j, strict > = first index).
            // numpy semantics: (dx^2 + dy^2) + dz^2, each op rn, no FMA.
            float bestv = -1.0f;
            int bestj = 0;
#pragma unroll
            for (int i = 0; i < PAIRS; ++i) {
                f2 dx = pk_add(x2[i], ncx);
                f2 dy = pk_add(y2[i], ncy);
                f2 dz = pk_add(z2[i], ncz);
                f2 sx = pk_mul(dx, dx);
                f2 sy = pk_mul(dy, dy);
                f2 t  = pk_add(sx, sy);
                f2 sz = pk_mul(dz, dz);
                f2 d  = pk_add(t, sz);
                float nd0 = fminf(dist2[i].x, d.x);
                float nd1 = fminf(dist2[i].y, d.y);
                dist2[i].x = nd0;
                dist2[i].y = nd1;
                if (nd0 > bestv) { bestv = nd0; bestj = 2 * i; }
                if (nd1 > bestv) { bestv = nd1; bestj = 2 * i + 1; }
            }
            int bestp = tid + bestj * FPS_T;
            // max-key, min-index tie-break (dist >= 0 -> float bits monotone)
            unsigned long long key =
                ((unsigned long long)__float_as_uint(bestv) << 13) |
                (unsigned)(8191 - bestp);

            // wave max, all-DPP (VALU pipe only): lane 63 gets wave max
            key = wave_max_dir(key);
            if (lane == 63) slots[g & 1][wid] = key;
            __syncthreads();

            const unsigned long long* sp = slots[g & 1];
            unsigned long long best = max64(max64(sp[0], sp[1]),
                                            max64(sp[2], sp[3]));
            far = 8191 - (int)(best & 0x1FFFULL);
        }

        __syncthreads();   // ctr_lds[last] written by tid 0
        // flush centroids to global, coalesced
        float* ctr = out_ctr + (size_t)b * NGRP * 3;
        for (int i = tid; i < NGRP * 3; i += FPS_T) ctr[i] = ctr_lds[i];

    } else {
        // ================= kNN role (R6-proven, s_sleep spin) =================
        const int wid  = tid >> 6;
        const int lane = tid & 63;
        const int W = (blockIdx.x - BATCH) * FPS_NW + wid;   // [0, 960)

        // enumerate centers in ascending-g order (availability order):
        // e = g*8 + b  ->  wave W handles e = W, W+960, ...
        for (int e = W; e < BATCH * NGRP; e += KNN_WAVES) {
            const int g  = e >> 3;
            const int b  = e & 7;
            const int bg = b * NGRP + g;
            const float* base = pts + (size_t)b * NPTS * NCH;

            // spin until fps publishes this center's index
            unsigned fidx;
            if (lane == 0) {
                while ((fidx = __hip_atomic_load(&faridx[bg * fstride],
                                                 __ATOMIC_RELAXED,
                                                 __HIP_MEMORY_SCOPE_AGENT)) == 0xFFFFFFFFu)
                    __builtin_amdgcn_s_sleep(8);
            }
            fidx = (unsigned)__shfl((int)fidx, 0, 64);

            const float cx = base[fidx * NCH + 0];
            const float cy = base[fidx * NCH + 1];
            const float cz = base[fidx * NCH + 2];
            const float cc = __fadd_rn(__fadd_rn(__fmul_rn(cx, cx), __fmul_rn(cy, cy)),
                                       __fmul_rn(cz, cz));

            // chunk 0 -> bitonic sort 64 keys across the wave
            unsigned long long R = knn_key(base, lane, cx, cy, cz, cc);
#pragma unroll
            for (int k = 2; k <= 64; k <<= 1) {
#pragma unroll
                for (int j = k >> 1; j > 0; j >>= 1) {
                    unsigned long long o = __shfl_xor(R, j, 64);
                    bool takeMin = (((lane & k) == 0) == ((lane & j) == 0));
                    unsigned long long mn = (o < R) ? o : R;
                    unsigned long long mx = (o < R) ? R : o;
                    R = takeMin ? mn : mx;
                }
            }
            unsigned long long R31 = __shfl(R, 31, 64);

            // stream remaining chunks; insert candidates beating current 32nd
            for (int c = 1; c < NPTS / 64; ++c) {
                unsigned long long key = knn_key(base, c * 64 + lane, cx, cy, cz, cc);
                unsigned long long qual = __ballot(key < R31);
                while (qual) {
                    int src = __ffsll(qual) - 1;
                    qual &= qual - 1;
                    unsigned long long bk = __shfl(key, src, 64);
                    int rank = __popcll(__ballot(R < bk));
                    unsigned long long Rp = __shfl_up(R, 1, 64);
                    R = (lane == rank) ? bk : ((lane > rank) ? Rp : R);
                    R31 = __shfl(R, 31, 64);
                }
            }

            // gather: lanes 0..31 hold the sorted top-32
            if (lane < KNN) {
                int idx = (int)(R & 8191ULL);
                const float* s = base + (size_t)idx * NCH;
                float* d = out_nb + ((size_t)bg * KNN + lane) * NCH;
                d[0] = s[0] - cx;
                d[1] = s[1] - cy;
                d[2] = s[2] - cz;
                d[3] = s[3];
                d[4] = s[4];
                d[5] = s[5];
            }
        }
    }
}

extern "C" void kernel_launch(void* const* d_in, const int* in_sizes, int n_in,
                              void* d_out, int out_size, void* d_ws, size_t ws_size,
                              hipStream_t stream) {
    const float* pts = (const float*)d_in[0];
    float* out = (float*)d_out;
    float* out_nb  = out;                                    // (8,512,32,6)
    float* out_ctr = out + (size_t)BATCH * NGRP * KNN * NCH; // (8,512,3)

    // per-center published index; 64B stride => 1 writer + 1 reader per line
    const size_t nctr = (size_t)BATCH * NGRP;
    int fstride = (ws_size >= nctr * 16 * sizeof(unsigned)) ? 16 : 1;
    unsigned int* faridx = (unsigned int*)d_ws;

    hipMemsetAsync(d_ws, 0xFF, nctr * (size_t)fstride * sizeof(unsigned), stream);
    hipLaunchKernelGGL(fused_kernel, dim3(NBLK), dim3(FPS_T), 0, stream,
                       pts, out_ctr, out_nb, faridx, fstride);
}